// Round 13
// baseline (912.685 us; speedup 1.0000x reference)
//
#include <hip/hip_runtime.h>

// ======================= DIAGNOSTIC ROUND =======================
// REP amplifies each kernel's compute x16 (idempotent / last-rep-guarded)
// so every kernel clears the harness's 40-us poison-fill curtain and shows
// in rocprof top-5 with its own counters. Set REP=1 to restore R12 timing.
#define REP 16

#define BB 16
#define PP 131072
#define GG 64
#define THRESH 0.35f
#define RMAX 0.086f
#define NCELL 32
#define NCHM 64
#define CPM 2048
#define NCHL 64
#define CPL 2048
#define NCC 64
#define CPC 2048

#define OFF_BESTP   0
#define OFF_BEST64  524288
#define OFF_H1TOT   532480
#define OFF_NPOSP   794624
#define OFF_PCP     798720
#define OFF_LOCP    802816
#define OFF_CIDX    806912
#define OFF_NEGS    806976
#define OFF_RESN    807040
#define OFF_RESK    807104
#define OFF_RESC    807168
#define OFF_RESL    807232
#define OFF_PU8     807296
#define OFF_KEYS    2904448
#define OFF_CAND    11293056

// ---------------- kernel 1: raster mask + match ----------------
__global__ __launch_bounds__(256) void k_match(
    const float* __restrict__ priorbox, const float* __restrict__ targets,
    unsigned long long* __restrict__ bestp, unsigned char* __restrict__ pu8,
    unsigned* __restrict__ h1tot, unsigned* __restrict__ cidx,
    float* __restrict__ negs)
{
    __shared__ unsigned msk[2 * NCELL * NCELL];
    __shared__ float4 gxy[GG];
    __shared__ unsigned long long sbest[GG];
    const int b = blockIdx.y, chunk = blockIdx.x, tid = threadIdx.x;

    if (tid < 64) h1tot[b * 4096 + chunk * 64 + tid] = 0u;
    if (chunk == 0 && tid == 0) { cidx[b] = 0u; negs[b] = 0.f; }
    if (tid < GG) {
        const float* t = targets + (size_t)(b * GG + tid) * 5;
        gxy[tid] = make_float4(t[1], t[0], t[3], t[2]);
        sbest[tid] = 0ull;
    }
    __syncthreads();

#pragma unroll 1
    for (int rep = 0; rep < REP; ++rep) {
        for (int i = tid; i < 2 * NCELL * NCELL; i += 256) msk[i] = 0u;
        __syncthreads();
        {   // rasterize (idempotent per rep)
            const int g = tid & 63, strip = tid >> 6;
            float4 a = gxy[g];
            int cx0 = max(0, (int)((a.x - RMAX) * (float)NCELL));
            int cx1 = min(NCELL - 1, (int)ceilf((a.z + RMAX) * (float)NCELL) - 1);
            int cy0 = max(0, (int)((a.y - RMAX) * (float)NCELL));
            int cy1 = min(NCELL - 1, (int)ceilf((a.w + RMAX) * (float)NCELL) - 1);
            unsigned bit = 1u << (g & 31);
            const int word = (g >> 5);
            for (int cy = cy0 + strip; cy <= cy1; cy += 4)
                for (int cx = cx0; cx <= cx1; cx++)
                    atomicOr(&msk[2 * (cy * NCELL + cx) + word], bit);
        }
        __syncthreads();

#pragma unroll
        for (int j = 0; j < 8; j++) {
            const int p = chunk * CPM + j * 256 + tid;
            float4 pr = *reinterpret_cast<const float4*>(priorbox + (size_t)p * 4);
            float hx = 0.5f * pr.z, hy = 0.5f * pr.w;
            float px1 = pr.x - hx, py1 = pr.y - hy;
            float px2 = pr.x + hx, py2 = pr.y + hy;
            float par = (px2 - px1) * (py2 - py1);
            int cx = min(NCELL - 1, max(0, (int)(pr.x * (float)NCELL)));
            int cy = min(NCELL - 1, max(0, (int)(pr.y * (float)NCELL)));
            uint2 mm = *reinterpret_cast<uint2*>(&msk[2 * (cy * NCELL + cx)]);
            unsigned long long m = ((unsigned long long)mm.y << 32) | mm.x;
            const unsigned long long notp = (unsigned long long)(~(unsigned)p);
            float bv = -1.f; int bg = 0;
            while (m) {
                const int g0 = __ffsll(m) - 1; m &= m - 1;
                const bool has1 = (m != 0ull);
                const int g1 = has1 ? (__ffsll(m) - 1) : g0;
                if (has1) m &= m - 1;
                float4 a0 = gxy[g0];
                float4 a1 = gxy[g1];
                float w0 = fmaxf(fminf(a0.z, px2) - fmaxf(a0.x, px1), 0.f);
                float h0 = fmaxf(fminf(a0.w, py2) - fmaxf(a0.y, py1), 0.f);
                float w1 = fmaxf(fminf(a1.z, px2) - fmaxf(a1.x, px1), 0.f);
                float h1 = fmaxf(fminf(a1.w, py2) - fmaxf(a1.y, py1), 0.f);
                float ar0 = (a0.z - a0.x) * (a0.w - a0.y);
                float ar1 = (a1.z - a1.x) * (a1.w - a1.y);
                float i0 = w0 * h0, i1 = w1 * h1;
                float v0 = i0 * __builtin_amdgcn_rcpf(ar0 + par - i0);
                float v1 = i1 * __builtin_amdgcn_rcpf(ar1 + par - i1);
                if (v0 > bv) { bv = v0; bg = g0; }
                if (has1 && v1 > bv) { bv = v1; bg = g1; }
                if (v0 > 0.f)
                    atomicMax(&sbest[g0],
                              (((unsigned long long)__float_as_uint(v0)) << 32) | notp);
                if (has1 && v1 > 0.f)
                    atomicMax(&sbest[g1],
                              (((unsigned long long)__float_as_uint(v1)) << 32) | notp);
            }
            pu8[(size_t)b * PP + p] = (unsigned char)(bg | ((bv >= THRESH) ? 0x80 : 0));
        }
        __syncthreads();
    }
    if (tid < GG) bestp[(b * NCHM + chunk) * GG + tid] = sbest[tid];
}

// ---------------- kernel 1b: reduce bestp over chunks ----------------
__global__ void k_bred(const unsigned long long* __restrict__ bestp,
                       unsigned long long* __restrict__ best64)
{
    const int b = blockIdx.x, g = threadIdx.x;
#pragma unroll 1
    for (int rep = 0; rep < REP; ++rep) {
        unsigned long long m = 0ull;
#pragma unroll 8
        for (int c = 0; c < NCHM; c++) {
            unsigned long long v = bestp[(b * NCHM + c) * GG + g];
            m = v > m ? v : m;
        }
        best64[b * GG + g] = m;                        // idempotent per rep
    }
}

// ---------------- kernel 2: loss + keys + global hist ----------------
__global__ __launch_bounds__(256) void k_loss(
    const float* __restrict__ loc_preds, const float* __restrict__ cls_preds,
    const float* __restrict__ priorbox, const float* __restrict__ targets,
    const unsigned long long* __restrict__ best64, const unsigned char* __restrict__ pu8,
    unsigned* __restrict__ keys, unsigned* __restrict__ h1tot,
    int* __restrict__ nposp, float* __restrict__ pcp, float* __restrict__ locp)
{
    __shared__ unsigned hcnt[4096];
    __shared__ unsigned ovr[CPL];
    __shared__ float4 gxy[GG];
    __shared__ float glab[GG];
    __shared__ float sred[8];
    __shared__ int sredi[4];
    const int b = blockIdx.y, chunk = blockIdx.x, tid = threadIdx.x;
    const int lane = tid & 63, wid = tid >> 6;

    if (tid < GG) {
        const float* t = targets + (size_t)(b * GG + tid) * 5;
        gxy[tid] = make_float4(t[1], t[0], t[3], t[2]);
        glab[tid] = t[4];
    }

    float locpart = 0.f, clspart = 0.f; int cnt = 0;
#pragma unroll 1
    for (int rep = 0; rep < REP; ++rep) {
        for (int i = tid; i < 4096; i += 256) hcnt[i] = 0u;
        for (int i = tid; i < CPL; i += 256) ovr[i] = 0u;
        __syncthreads();
        if (tid < GG) {
            unsigned long long m = best64[b * GG + tid];
            if (m) {
                unsigned p = ~((unsigned)(m & 0xFFFFFFFFull));
                if ((int)(p >> 11) == chunk)
                    atomicMax(&ovr[p & (CPL - 1)], (unsigned)tid + 1u);
            }
        }
        __syncthreads();

        locpart = 0.f; clspart = 0.f; cnt = 0;
#pragma unroll
        for (int j = 0; j < 8; j++) {
            const int plocal = j * 256 + tid;
            const size_t ip = (size_t)b * PP + chunk * CPL + plocal;
            const unsigned m8 = pu8[ip];
            int g = m8 & 63;
            bool pos = (m8 >> 7) != 0;
            const unsigned o = ovr[plocal];
            if (o) { pos = true; g = (int)o - 1; }
            const float2 cl = *reinterpret_cast<const float2*>(cls_preds + ip * 2);
            const float mx = fmaxf(cl.x, cl.y);
            const float lse = mx + log1pf(expf(fminf(cl.x, cl.y) - mx));
            unsigned key = 0u;
            if (pos && glab[g] > 0.f) {
                float gathered = (((int)glab[g]) == 0) ? cl.x : cl.y;
                clspart += lse - gathered;
                cnt++;
                const int p = chunk * CPL + plocal;
                float4 pr = *reinterpret_cast<const float4*>(priorbox + (size_t)p * 4);
                float4 gt = gxy[g];
                float gcx = ((gt.x + gt.z) * 0.5f - pr.x) / (0.1f * pr.z);
                float gcy = ((gt.y + gt.w) * 0.5f - pr.y) / (0.1f * pr.w);
                float gw = logf((gt.z - gt.x) / pr.z) / 0.2f;
                float gh = logf((gt.w - gt.y) / pr.w) / 0.2f;
                float4 lp = *reinterpret_cast<const float4*>(loc_preds + ip * 4);
                float d0 = lp.x - gcx, d1 = lp.y - gcy, d2 = lp.z - gw, d3 = lp.w - gh;
                float a0 = fabsf(d0), a1 = fabsf(d1), a2 = fabsf(d2), a3 = fabsf(d3);
                locpart += ((a0 < 1.f) ? 0.5f * d0 * d0 : a0 - 0.5f)
                         + ((a1 < 1.f) ? 0.5f * d1 * d1 : a1 - 0.5f)
                         + ((a2 < 1.f) ? 0.5f * d2 * d2 : a2 - 0.5f)
                         + ((a3 < 1.f) ? 0.5f * d3 * d3 : a3 - 0.5f);
            } else {
                float lc = lse - cl.x;
                key = __float_as_uint(lc);
                atomicAdd(&hcnt[key >> 20], 1u);
            }
            keys[ip] = key;                            // idempotent per rep
        }
        __syncthreads();                               // hcnt settled before next zero
    }

    for (int o = 32; o; o >>= 1) {
        locpart += __shfl_xor(locpart, o);
        clspart += __shfl_xor(clspart, o);
        cnt     += __shfl_xor(cnt, o);
    }
    if (lane == 0) { sred[wid] = locpart; sred[4 + wid] = clspart; sredi[wid] = cnt; }
    __syncthreads();
    if (tid == 0) {
        float l = sred[0] + sred[1] + sred[2] + sred[3];
        float c = sred[4] + sred[5] + sred[6] + sred[7];
        int n = sredi[0] + sredi[1] + sredi[2] + sredi[3];
        nposp[b * NCHL + chunk] = n;
        pcp[b * NCHL + chunk] = c;
        locp[b * NCHL + chunk] = l;
    }
    __syncthreads();
    for (int i = tid; i < 4096; i += 256) {
        unsigned cc = hcnt[i];
        if (cc) atomicAdd(&h1tot[b * 4096 + i], cc);   // global flush ONCE
    }
}

// ---------------- parallel descending k-th finder ----------------
template <int NBINS>
__device__ void find_kth_par(const unsigned* __restrict__ h, int k, int* sel, int* krem)
{
    constexpr int PER = NBINS / 256;
    __shared__ unsigned wsum_[4];
    __shared__ int res_[2];
    const int tid = threadIdx.x, lane = tid & 63, wid = tid >> 6;
    __syncthreads();
    unsigned s = 0;
#pragma unroll
    for (int i = 0; i < PER; i++) s += h[NBINS - 1 - (tid * PER + i)];
    unsigned incl = s;
    for (int d = 1; d < 64; d <<= 1) {
        unsigned t = __shfl_up(incl, d);
        if (lane >= d) incl += t;
    }
    if (lane == 63) wsum_[wid] = incl;
    if (tid == 0) { res_[0] = -1; res_[1] = 0; }
    __syncthreads();
    unsigned woff = 0;
    for (int w = 0; w < 4; w++) woff += (w < wid) ? wsum_[w] : 0u;
    const unsigned texcl = woff + incl - s;
    if (k > 0 && texcl < (unsigned)k && texcl + s >= (unsigned)k) {
        unsigned run = texcl;
        for (int i = 0; i < PER; i++) {
            unsigned hv = h[NBINS - 1 - (tid * PER + i)];
            run += hv;
            if (run >= (unsigned)k) {
                res_[0] = NBINS - 1 - (tid * PER + i);
                res_[1] = k - (int)(run - hv);
                break;
            }
        }
    }
    __syncthreads();
    *sel = res_[0]; *krem = res_[1];
}

__device__ float block_sum_f(float v)
{
    __shared__ float rs[4];
    const int tid = threadIdx.x;
    __syncthreads();
    for (int o = 32; o; o >>= 1) v += __shfl_xor(v, o);
    if ((tid & 63) == 0) rs[tid >> 6] = v;
    __syncthreads();
    return rs[0] + rs[1] + rs[2] + rs[3];
}

__device__ int np_of_image(const int* __restrict__ nposp, int b)
{
    __shared__ int snp;
    const int tid = threadIdx.x;
    int v = (tid < 64) ? nposp[b * NCHL + tid] : 0;
    if (tid < 64) {
        for (int o = 32; o; o >>= 1) v += __shfl_xor(v, o);
        if (tid == 0) snp = v;
    }
    __syncthreads();
    return snp;
}

// ---------------- kernel 3: sel1 + negsum + compact ----------------
__global__ __launch_bounds__(256) void k_compact(
    const unsigned* __restrict__ keys, const unsigned* __restrict__ h1tot,
    const int* __restrict__ nposp, unsigned* __restrict__ cand,
    unsigned* __restrict__ cidx, float* __restrict__ negs)
{
    __shared__ unsigned wcnt[4], wbase[4];
    __shared__ unsigned bbase;
    const int b = blockIdx.y, chunk = blockIdx.x, tid = threadIdx.x;
    const int lane = tid & 63, wid = tid >> 6;

    const int np = np_of_image(nposp, b);
    const int k = min(3 * np, PP - 1);
    unsigned kv[8];
    unsigned long long mv[8];
    int sel1 = -1, kk1 = 0;
    unsigned wn = 0;
    float nsum = 0.f;

#pragma unroll 1
    for (int rep = 0; rep < REP; ++rep) {
#pragma unroll
        for (int j = 0; j < 8; j++)
            kv[j] = keys[(size_t)b * PP + chunk * CPC + j * 256 + tid];
        find_kth_par<4096>(h1tot + b * 4096, k, &sel1, &kk1);
        const unsigned s1r = (unsigned)sel1;
        float nv = 0.f;
        if (sel1 >= 0) {
#pragma unroll
            for (int j = 0; j < 8; j++)
                if ((kv[j] >> 20) > s1r) nv += __uint_as_float(kv[j]);
        }
        nsum = block_sum_f(nv);
        wn = 0;
#pragma unroll
        for (int j = 0; j < 8; j++) {
            mv[j] = __ballot((kv[j] >> 20) == s1r);
            wn += (unsigned)__popcll(mv[j]);
        }
        asm volatile("" :: "v"(nsum), "v"(wn), "v"(sel1));  // keep reps live
    }

    const unsigned s1 = (unsigned)sel1;
    if (tid == 0 && nsum != 0.f) atomicAdd(&negs[b], nsum);
    if (lane == 0) wcnt[wid] = wn;
    __syncthreads();
    if (tid == 0) {
        unsigned run = 0;
        for (int w = 0; w < 4; w++) { wbase[w] = run; run += wcnt[w]; }
        bbase = run ? atomicAdd(&cidx[b], run) : 0u;
    }
    __syncthreads();
    unsigned run = bbase + wbase[wid];
    const unsigned long long lanemask = (1ull << lane) - 1ull;
#pragma unroll
    for (int j = 0; j < 8; j++) {
        if ((kv[j] >> 20) == s1)
            cand[(size_t)b * PP + run + (unsigned)__popcll(mv[j] & lanemask)] = kv[j];
        run += (unsigned)__popcll(mv[j]);
    }
}

// ---------------- kernel 4: exact top-k among candidates ----------------
__global__ __launch_bounds__(256) void k_select(
    const unsigned* __restrict__ cand, const unsigned* __restrict__ cidx,
    const unsigned* __restrict__ h1tot, const int* __restrict__ nposp,
    const float* __restrict__ pcp, const float* __restrict__ locp,
    const float* __restrict__ negs,
    int* __restrict__ resn, int* __restrict__ resk,
    float* __restrict__ resc, float* __restrict__ resl)
{
    __shared__ unsigned ch[1024];
    __shared__ float cs[1024];
    const int b = blockIdx.x, tid = threadIdx.x;

    const int np = np_of_image(nposp, b);
    const int k = min(3 * np, PP - 1);
    int sel1, kk1, sel2, kk2, sel3, needeq;
    float pcsum = 0.f, locsum = 0.f, sumhi2 = 0.f, sumhi3 = 0.f;
    unsigned ncand = 0;

#pragma unroll 1
    for (int rep = 0; rep < REP; ++rep) {
        find_kth_par<4096>(h1tot + b * 4096, k, &sel1, &kk1);
        ncand = cidx[b];

        float pv = (tid < 64) ? pcp[b * NCHL + tid] : 0.f;
        float lv = (tid < 64) ? locp[b * NCHL + tid] : 0.f;
        pcsum = block_sum_f(pv);
        locsum = block_sum_f(lv);

        for (int i = tid; i < 1024; i += 256) { ch[i] = 0u; cs[i] = 0.f; }
        __syncthreads();
        for (unsigned i = tid; i < ncand; i += 256) {
            unsigned v = cand[(size_t)b * PP + i];
            unsigned bin = (v >> 10) & 1023u;
            atomicAdd(&ch[bin], 1u);
            atomicAdd(&cs[bin], __uint_as_float(v));
        }
        __syncthreads();
        find_kth_par<1024>(ch, (sel1 < 0) ? 0 : kk1, &sel2, &kk2);
        float s2v = 0.f;
        for (int i = tid * 4; i < tid * 4 + 4; i++)
            if (sel2 >= 0 && i > sel2) s2v += cs[i];
        sumhi2 = block_sum_f(s2v);

        __syncthreads();
        for (int i = tid; i < 1024; i += 256) { ch[i] = 0u; cs[i] = 0.f; }
        __syncthreads();
        if (sel2 >= 0) {
            for (unsigned i = tid; i < ncand; i += 256) {
                unsigned v = cand[(size_t)b * PP + i];
                if (((v >> 10) & 1023u) == (unsigned)sel2) {
                    atomicAdd(&ch[v & 1023u], 1u);
                    atomicAdd(&cs[v & 1023u], __uint_as_float(v));
                }
            }
        }
        __syncthreads();
        find_kth_par<1024>(ch, (sel2 < 0) ? 0 : kk2, &sel3, &needeq);
        float s3v = 0.f;
        for (int i = tid * 4; i < tid * 4 + 4; i++)
            if (sel3 >= 0 && i > sel3) s3v += cs[i];
        sumhi3 = block_sum_f(s3v);
        asm volatile("" :: "v"(pcsum), "v"(locsum), "v"(sumhi2), "v"(sumhi3),
                          "v"(sel3), "v"(needeq));     // keep reps live
    }

    if (tid == 0) {
        float add = 0.f;
        if (sel3 >= 0 && needeq > 0) {
            unsigned Kstar = ((unsigned)sel1 << 20) | ((unsigned)sel2 << 10) | (unsigned)sel3;
            add = needeq * __uint_as_float(Kstar);
        }
        resn[b] = np;
        resk[b] = k;
        resc[b] = pcsum + negs[b] + sumhi2 + sumhi3 + add;
        resl[b] = locsum;
    }
}

// ---------------- kernel 5: cross-image combine ----------------
__global__ void k_final(const int* __restrict__ resn, const int* __restrict__ resk,
                        const float* __restrict__ resc, const float* __restrict__ resl,
                        float* __restrict__ out)
{
    const int t = threadIdx.x;
    int n = 0, kk = 0; float c = 0.f, l = 0.f;
    if (t < BB) { n = resn[t]; kk = resk[t]; c = resc[t]; l = resl[t]; }
    for (int o = 8; o; o >>= 1) {
        n += __shfl_xor(n, o); kk += __shfl_xor(kk, o);
        c += __shfl_xor(c, o); l += __shfl_xor(l, o);
    }
    if (t == 0) {
        long long maskc = (long long)n + kk;
        float denom_loc = (float)((4 * n > 1) ? 4 * n : 1);
        float denom_cls = (float)((maskc > 1) ? maskc : 1);
        float loss_loc = l / denom_loc;
        float loss_cls = c / denom_cls;
        out[0] = (loss_cls + loss_loc) / (float)n;
        out[1] = loss_loc;
        out[2] = loss_cls;
    }
}

extern "C" void kernel_launch(void* const* d_in, const int* in_sizes, int n_in,
                              void* d_out, int out_size, void* d_ws, size_t ws_size,
                              hipStream_t stream)
{
    const float* loc_preds = (const float*)d_in[0];
    const float* cls_preds = (const float*)d_in[1];
    const float* priorbox  = (const float*)d_in[2];
    const float* targets   = (const float*)d_in[3];
    float* out = (float*)d_out;

    char* ws = (char*)d_ws;
    unsigned long long* bestp  = (unsigned long long*)(ws + OFF_BESTP);
    unsigned long long* best64 = (unsigned long long*)(ws + OFF_BEST64);
    unsigned* h1tot = (unsigned*)(ws + OFF_H1TOT);
    int*      nposp = (int*)(ws + OFF_NPOSP);
    float*    pcp   = (float*)(ws + OFF_PCP);
    float*    locp  = (float*)(ws + OFF_LOCP);
    unsigned* cidx  = (unsigned*)(ws + OFF_CIDX);
    float*    negs  = (float*)(ws + OFF_NEGS);
    int*      resn  = (int*)(ws + OFF_RESN);
    int*      resk  = (int*)(ws + OFF_RESK);
    float*    resc  = (float*)(ws + OFF_RESC);
    float*    resl  = (float*)(ws + OFF_RESL);
    unsigned char* pu8 = (unsigned char*)(ws + OFF_PU8);
    unsigned* keys  = (unsigned*)(ws + OFF_KEYS);
    unsigned* cand  = (unsigned*)(ws + OFF_CAND);

    k_match<<<dim3(NCHM, BB), 256, 0, stream>>>(priorbox, targets, bestp, pu8,
                                                h1tot, cidx, negs);
    k_bred<<<BB, 64, 0, stream>>>(bestp, best64);
    k_loss<<<dim3(NCHL, BB), 256, 0, stream>>>(loc_preds, cls_preds, priorbox, targets,
                                               best64, pu8, keys, h1tot,
                                               nposp, pcp, locp);
    k_compact<<<dim3(NCC, BB), 256, 0, stream>>>(keys, h1tot, nposp, cand, cidx, negs);
    k_select<<<BB, 256, 0, stream>>>(cand, cidx, h1tot, nposp, pcp, locp, negs,
                                     resn, resk, resc, resl);
    k_final<<<1, 64, 0, stream>>>(resn, resk, resc, resl, out);
}

// Round 14
// 125.419 us; speedup vs baseline: 7.2771x; 7.2771x over previous
//
#include <hip/hip_runtime.h>

#define BB 16
#define PP 131072
#define GG 64
#define THRESH 0.35f
#define RMAX 0.086f          // max prior half-extent 0.085 + slop margin
#define NCELL 32             // 32x32 cell grid (8KB LDS mask)
#define NCHM 64              // match chunks per image
#define CPM 2048
#define NCHL 64              // loss chunks per image
#define CPL 2048
#define NCC 64               // compact chunks per image
#define CPC 2048

// ---------------- workspace layout (bytes) ----------------
// No host-side zeroing: partials unconditional; cidx/negs/done zeroed by k_match
// (consumed >=2 kernel boundaries later).
#define OFF_BESTP   0          // u64[BB][NCHM][64]  524288  (plain stores)
#define OFF_H1TOT   524288     // u32[BB][4096]      262144  (zeroed by k_match)
#define OFF_NPOSP   786432     // i32[BB][NCHL]      4096
#define OFF_PCP     790528     // f32[BB][NCHL]      4096
#define OFF_LOCP    794624     // f32[BB][NCHL]      4096
#define OFF_CIDX    798720     // u32[BB]            64
#define OFF_NEGS    798784     // f32[BB]            64
#define OFF_DONE    798848     // u32                64
#define OFF_RESN    798912     // i32[BB]
#define OFF_RESK    798976     // i32[BB]
#define OFF_RESC    799040     // f32[BB]
#define OFF_RESL    799104     // f32[BB]
#define OFF_PU8     799168     // u8[BB*PP]   2097152
#define OFF_KEYS    2896320    // u32[BB*PP]  8388608
#define OFF_CAND    11284928   // u32[BB*PP]  8388608   (total ~19.7 MB)

// ---------------- kernel 1: raster mask + match (two-phase, 32-bit atomics only) ----
// grid (NCHM, BB) x 256; 8 priors/thread.
// P1: per-prior best gt (bv/bg) + per-g block-max IoU via NON-RETURNING ds_max_u32
//     (f32 bits monotone for v>0). The R12 hot loop's u64 LDS atomicMax was the
//     31us whale: 64-bit LDS atomicMax lowers to a divergent CAS loop.
// P2: re-walk mask; on the rare v==blockmax hits, ds_min_u32 of p (min-p tiebreak).
__global__ __launch_bounds__(256) void k_match(
    const float* __restrict__ priorbox, const float* __restrict__ targets,
    unsigned long long* __restrict__ bestp, unsigned char* __restrict__ pu8,
    unsigned* __restrict__ h1tot, unsigned* __restrict__ cidx,
    float* __restrict__ negs, unsigned* __restrict__ done)
{
    __shared__ unsigned msk[2 * NCELL * NCELL];        // u64 per cell, interleaved
    __shared__ float4 gxy[GG];
    __shared__ unsigned sbv[GG];                       // block-max iou bits per g
    __shared__ unsigned sbp[GG];                       // min p among max achievers
    const int b = blockIdx.y, chunk = blockIdx.x, tid = threadIdx.x;

    if (tid < 64) h1tot[b * 4096 + chunk * 64 + tid] = 0u;
    if (chunk == 0 && tid == 0) { cidx[b] = 0u; negs[b] = 0.f; if (b == 0) *done = 0u; }
    for (int i = tid; i < 2 * NCELL * NCELL; i += 256) msk[i] = 0u;
    if (tid < GG) {
        const float* t = targets + (size_t)(b * GG + tid) * 5;
        gxy[tid] = make_float4(t[1], t[0], t[3], t[2]); // gts = t[[1,0,3,2]]
        sbv[tid] = 0u;
        sbp[tid] = 0xFFFFFFFFu;
    }
    __syncthreads();

    {   // rasterize expanded gt boxes into the cell bitmask
        const int g = tid & 63, strip = tid >> 6;
        float4 a = gxy[g];
        int cx0 = max(0, (int)((a.x - RMAX) * (float)NCELL));
        int cx1 = min(NCELL - 1, (int)ceilf((a.z + RMAX) * (float)NCELL) - 1);
        int cy0 = max(0, (int)((a.y - RMAX) * (float)NCELL));
        int cy1 = min(NCELL - 1, (int)ceilf((a.w + RMAX) * (float)NCELL) - 1);
        unsigned bit = 1u << (g & 31);
        const int word = (g >> 5);
        for (int cy = cy0 + strip; cy <= cy1; cy += 4)
            for (int cx = cx0; cx <= cx1; cx++)
                atomicOr(&msk[2 * (cy * NCELL + cx) + word], bit);
    }
    __syncthreads();

    // -------- P1 --------
#pragma unroll
    for (int j = 0; j < 8; j++) {
        const int p = chunk * CPM + j * 256 + tid;
        float4 pr = *reinterpret_cast<const float4*>(priorbox + (size_t)p * 4);
        float hx = 0.5f * pr.z, hy = 0.5f * pr.w;
        float px1 = pr.x - hx, py1 = pr.y - hy;
        float px2 = pr.x + hx, py2 = pr.y + hy;
        float par = (px2 - px1) * (py2 - py1);
        int cx = min(NCELL - 1, max(0, (int)(pr.x * (float)NCELL)));
        int cy = min(NCELL - 1, max(0, (int)(pr.y * (float)NCELL)));
        unsigned m0 = msk[2 * (cy * NCELL + cx)];
        unsigned m1 = msk[2 * (cy * NCELL + cx) + 1];
        float bv = -1.f; int bg = 0;
#define VISIT1(GIDX)                                                        \
        {                                                                   \
            float4 a = gxy[GIDX];                                           \
            float w = fmaxf(fminf(a.z, px2) - fmaxf(a.x, px1), 0.f);        \
            float h = fmaxf(fminf(a.w, py2) - fmaxf(a.y, py1), 0.f);        \
            float inter = w * h;                                            \
            float ar = (a.z - a.x) * (a.w - a.y);                           \
            float v = inter * __builtin_amdgcn_rcpf(ar + par - inter);      \
            if (v > bv) { bv = v; bg = (GIDX); }                            \
            if (v > 0.f) atomicMax(&sbv[GIDX], __float_as_uint(v));         \
        }
        while (m0) { const int g = __ffs(m0) - 1; m0 &= m0 - 1; VISIT1(g); }
        while (m1) { const int g = 32 + __ffs(m1) - 1; m1 &= m1 - 1; VISIT1(g); }
#undef VISIT1
        pu8[(size_t)b * PP + p] = (unsigned char)(bg | ((bv >= THRESH) ? 0x80 : 0));
    }
    __syncthreads();

    // -------- P2: resolve min-p among block-max achievers --------
#pragma unroll
    for (int j = 0; j < 8; j++) {
        const int p = chunk * CPM + j * 256 + tid;
        float4 pr = *reinterpret_cast<const float4*>(priorbox + (size_t)p * 4);
        float hx = 0.5f * pr.z, hy = 0.5f * pr.w;
        float px1 = pr.x - hx, py1 = pr.y - hy;
        float px2 = pr.x + hx, py2 = pr.y + hy;
        float par = (px2 - px1) * (py2 - py1);
        int cx = min(NCELL - 1, max(0, (int)(pr.x * (float)NCELL)));
        int cy = min(NCELL - 1, max(0, (int)(pr.y * (float)NCELL)));
        unsigned m0 = msk[2 * (cy * NCELL + cx)];
        unsigned m1 = msk[2 * (cy * NCELL + cx) + 1];
#define VISIT2(GIDX)                                                        \
        {                                                                   \
            float4 a = gxy[GIDX];                                           \
            float w = fmaxf(fminf(a.z, px2) - fmaxf(a.x, px1), 0.f);        \
            float h = fmaxf(fminf(a.w, py2) - fmaxf(a.y, py1), 0.f);        \
            float inter = w * h;                                            \
            float ar = (a.z - a.x) * (a.w - a.y);                           \
            float v = inter * __builtin_amdgcn_rcpf(ar + par - inter);      \
            if (v > 0.f && __float_as_uint(v) == sbv[GIDX])                 \
                atomicMin(&sbp[GIDX], (unsigned)p);                         \
        }
        while (m0) { const int g = __ffs(m0) - 1; m0 &= m0 - 1; VISIT2(g); }
        while (m1) { const int g = 32 + __ffs(m1) - 1; m1 &= m1 - 1; VISIT2(g); }
#undef VISIT2
    }
    __syncthreads();
    if (tid < GG) {
        unsigned v = sbv[tid];
        bestp[(b * NCHM + chunk) * GG + tid] =
            v ? ((((unsigned long long)v) << 32) |
                 (unsigned long long)(~sbp[tid])) : 0ull;   // max v, then min p
    }
}

// ---------------- kernel 2: loss + keys + global hist (bred folded in) ----------------
// grid (NCHL, BB) x 256; 8 priors/thread.
__global__ __launch_bounds__(256) void k_loss(
    const float* __restrict__ loc_preds, const float* __restrict__ cls_preds,
    const float* __restrict__ priorbox, const float* __restrict__ targets,
    const unsigned long long* __restrict__ bestp, const unsigned char* __restrict__ pu8,
    unsigned* __restrict__ keys, unsigned* __restrict__ h1tot,
    int* __restrict__ nposp, float* __restrict__ pcp, float* __restrict__ locp)
{
    __shared__ unsigned hcnt[4096];
    __shared__ unsigned ovr[CPL];                      // forced-pos: g+1, max = later-g
    __shared__ float4 gxy[GG];
    __shared__ float glab[GG];
    __shared__ float sred[8];
    __shared__ int sredi[4];
    const int b = blockIdx.y, chunk = blockIdx.x, tid = threadIdx.x;
    const int lane = tid & 63, wid = tid >> 6;

    for (int i = tid; i < 4096; i += 256) hcnt[i] = 0u;
    for (int i = tid; i < CPL; i += 256) ovr[i] = 0u;
    if (tid < GG) {
        const float* t = targets + (size_t)(b * GG + tid) * 5;
        gxy[tid] = make_float4(t[1], t[0], t[3], t[2]);
        glab[tid] = t[4];
    }
    __syncthreads();
    if (tid < GG) {                                    // inline chunk reduce (ex-k_bred)
        unsigned long long m = 0ull;
#pragma unroll 8
        for (int c = 0; c < NCHM; c++) {
            unsigned long long v = bestp[(b * NCHM + c) * GG + tid];
            m = v > m ? v : m;
        }
        if (m) {
            unsigned p = ~((unsigned)(m & 0xFFFFFFFFull));
            if ((int)(p >> 11) == chunk)
                atomicMax(&ovr[p & (CPL - 1)], (unsigned)tid + 1u);  // later-g wins
        }
    }
    __syncthreads();

    float locpart = 0.f, clspart = 0.f; int cnt = 0;
#pragma unroll
    for (int j = 0; j < 8; j++) {
        const int plocal = j * 256 + tid;
        const size_t ip = (size_t)b * PP + chunk * CPL + plocal;
        const unsigned m8 = pu8[ip];
        int g = m8 & 63;
        bool pos = (m8 >> 7) != 0;
        const unsigned o = ovr[plocal];
        if (o) { pos = true; g = (int)o - 1; }
        const float2 cl = *reinterpret_cast<const float2*>(cls_preds + ip * 2);
        const float mx = fmaxf(cl.x, cl.y);
        const float lse = mx + log1pf(expf(fminf(cl.x, cl.y) - mx));
        unsigned key = 0u;
        if (pos && glab[g] > 0.f) {
            float gathered = (((int)glab[g]) == 0) ? cl.x : cl.y;
            clspart += lse - gathered;
            cnt++;
            const int p = chunk * CPL + plocal;
            float4 pr = *reinterpret_cast<const float4*>(priorbox + (size_t)p * 4);
            float4 gt = gxy[g];
            float gcx = ((gt.x + gt.z) * 0.5f - pr.x) / (0.1f * pr.z);
            float gcy = ((gt.y + gt.w) * 0.5f - pr.y) / (0.1f * pr.w);
            float gw = logf((gt.z - gt.x) / pr.z) / 0.2f;
            float gh = logf((gt.w - gt.y) / pr.w) / 0.2f;
            float4 lp = *reinterpret_cast<const float4*>(loc_preds + ip * 4);
            float d0 = lp.x - gcx, d1 = lp.y - gcy, d2 = lp.z - gw, d3 = lp.w - gh;
            float a0 = fabsf(d0), a1 = fabsf(d1), a2 = fabsf(d2), a3 = fabsf(d3);
            locpart += ((a0 < 1.f) ? 0.5f * d0 * d0 : a0 - 0.5f)
                     + ((a1 < 1.f) ? 0.5f * d1 * d1 : a1 - 0.5f)
                     + ((a2 < 1.f) ? 0.5f * d2 * d2 : a2 - 0.5f)
                     + ((a3 < 1.f) ? 0.5f * d3 * d3 : a3 - 0.5f);
        } else {
            float lc = lse - cl.x;                     // > 0 strictly for negs
            key = __float_as_uint(lc);
            atomicAdd(&hcnt[key >> 20], 1u);
        }
        keys[ip] = key;
    }

    for (int o = 32; o; o >>= 1) {
        locpart += __shfl_xor(locpart, o);
        clspart += __shfl_xor(clspart, o);
        cnt     += __shfl_xor(cnt, o);
    }
    if (lane == 0) { sred[wid] = locpart; sred[4 + wid] = clspart; sredi[wid] = cnt; }
    __syncthreads();
    if (tid == 0) {
        float l = sred[0] + sred[1] + sred[2] + sred[3];
        float c = sred[4] + sred[5] + sred[6] + sred[7];
        int n = sredi[0] + sredi[1] + sredi[2] + sredi[3];
        nposp[b * NCHL + chunk] = n;
        pcp[b * NCHL + chunk] = c;
        locp[b * NCHL + chunk] = l;
    }
    __syncthreads();
    for (int i = tid; i < 4096; i += 256) {
        unsigned cc = hcnt[i];
        if (cc) atomicAdd(&h1tot[b * 4096 + i], cc);
    }
}

// ---------------- parallel descending k-th finder (256-thread block) ----------------
template <int NBINS>
__device__ void find_kth_par(const unsigned* __restrict__ h, int k, int* sel, int* krem)
{
    constexpr int PER = NBINS / 256;
    __shared__ unsigned wsum_[4];
    __shared__ int res_[2];
    const int tid = threadIdx.x, lane = tid & 63, wid = tid >> 6;
    __syncthreads();
    unsigned s = 0;
#pragma unroll
    for (int i = 0; i < PER; i++) s += h[NBINS - 1 - (tid * PER + i)];
    unsigned incl = s;
    for (int d = 1; d < 64; d <<= 1) {
        unsigned t = __shfl_up(incl, d);
        if (lane >= d) incl += t;
    }
    if (lane == 63) wsum_[wid] = incl;
    if (tid == 0) { res_[0] = -1; res_[1] = 0; }
    __syncthreads();
    unsigned woff = 0;
    for (int w = 0; w < 4; w++) woff += (w < wid) ? wsum_[w] : 0u;
    const unsigned texcl = woff + incl - s;
    if (k > 0 && texcl < (unsigned)k && texcl + s >= (unsigned)k) {
        unsigned run = texcl;
        for (int i = 0; i < PER; i++) {
            unsigned hv = h[NBINS - 1 - (tid * PER + i)];
            run += hv;
            if (run >= (unsigned)k) {
                res_[0] = NBINS - 1 - (tid * PER + i);
                res_[1] = k - (int)(run - hv);
                break;
            }
        }
    }
    __syncthreads();
    *sel = res_[0]; *krem = res_[1];
}

__device__ float block_sum_f(float v)
{
    __shared__ float rs[4];
    const int tid = threadIdx.x;
    __syncthreads();
    for (int o = 32; o; o >>= 1) v += __shfl_xor(v, o);
    if ((tid & 63) == 0) rs[tid >> 6] = v;
    __syncthreads();
    return rs[0] + rs[1] + rs[2] + rs[3];
}

__device__ int np_of_image(const int* __restrict__ nposp, int b)
{
    __shared__ int snp;
    const int tid = threadIdx.x;
    int v = (tid < 64) ? nposp[b * NCHL + tid] : 0;
    if (tid < 64) {
        for (int o = 32; o; o >>= 1) v += __shfl_xor(v, o);
        if (tid == 0) snp = v;
    }
    __syncthreads();
    return snp;
}

// ---------------- kernel 3: sel1 (redundant) + negsum + compact ----------------
// grid (NCC, BB) x 256, 8 keys/thread; 1 returning atomic per block.
__global__ __launch_bounds__(256) void k_compact(
    const unsigned* __restrict__ keys, const unsigned* __restrict__ h1tot,
    const int* __restrict__ nposp, unsigned* __restrict__ cand,
    unsigned* __restrict__ cidx, float* __restrict__ negs)
{
    __shared__ unsigned wcnt[4], wbase[4];
    __shared__ unsigned bbase;
    const int b = blockIdx.y, chunk = blockIdx.x, tid = threadIdx.x;
    const int lane = tid & 63, wid = tid >> 6;

    unsigned kv[8];
#pragma unroll
    for (int j = 0; j < 8; j++)
        kv[j] = keys[(size_t)b * PP + chunk * CPC + j * 256 + tid];

    const int np = np_of_image(nposp, b);
    const int k = min(3 * np, PP - 1);
    int sel1, kk1;
    find_kth_par<4096>(h1tot + b * 4096, k, &sel1, &kk1);
    const unsigned s1 = (unsigned)sel1;                // -1 matches nothing

    float nv = 0.f;
    if (sel1 >= 0) {
#pragma unroll
        for (int j = 0; j < 8; j++)
            if ((kv[j] >> 20) > s1) nv += __uint_as_float(kv[j]);
    }
    float nsum = block_sum_f(nv);
    if (tid == 0 && nsum != 0.f) atomicAdd(&negs[b], nsum);

    unsigned long long mv[8];
    unsigned wn = 0;
#pragma unroll
    for (int j = 0; j < 8; j++) {
        mv[j] = __ballot((kv[j] >> 20) == s1);
        wn += (unsigned)__popcll(mv[j]);
    }
    if (lane == 0) wcnt[wid] = wn;
    __syncthreads();
    if (tid == 0) {
        unsigned run = 0;
        for (int w = 0; w < 4; w++) { wbase[w] = run; run += wcnt[w]; }
        bbase = run ? atomicAdd(&cidx[b], run) : 0u;
    }
    __syncthreads();
    unsigned run = bbase + wbase[wid];
    const unsigned long long lanemask = (1ull << lane) - 1ull;
#pragma unroll
    for (int j = 0; j < 8; j++) {
        if ((kv[j] >> 20) == s1)
            cand[(size_t)b * PP + run + (unsigned)__popcll(mv[j] & lanemask)] = kv[j];
        run += (unsigned)__popcll(mv[j]);
    }
}

// ---------------- kernel 4: exact top-k + per-image results + final (done-counter) ----
// grid BB x 256; last-done block combines the 3 outputs.
__global__ __launch_bounds__(256) void k_select(
    const unsigned* __restrict__ cand, const unsigned* __restrict__ cidx,
    const unsigned* __restrict__ h1tot, const int* __restrict__ nposp,
    const float* __restrict__ pcp, const float* __restrict__ locp,
    const float* __restrict__ negs,
    int* __restrict__ resn, int* __restrict__ resk,
    float* __restrict__ resc, float* __restrict__ resl,
    unsigned* __restrict__ done, float* __restrict__ out)
{
    __shared__ unsigned ch[1024];
    __shared__ float cs[1024];
    __shared__ int lastflag;
    const int b = blockIdx.x, tid = threadIdx.x;

    const int np = np_of_image(nposp, b);
    const int k = min(3 * np, PP - 1);
    int sel1, kk1;
    find_kth_par<4096>(h1tot + b * 4096, k, &sel1, &kk1);
    const unsigned ncand = cidx[b];

    float pv = (tid < 64) ? pcp[b * NCHL + tid] : 0.f;
    float lv = (tid < 64) ? locp[b * NCHL + tid] : 0.f;
    float pcsum = block_sum_f(pv);
    float locsum = block_sum_f(lv);

    for (int i = tid; i < 1024; i += 256) { ch[i] = 0u; cs[i] = 0.f; }
    __syncthreads();
    for (unsigned i = tid; i < ncand; i += 256) {
        unsigned v = cand[(size_t)b * PP + i];
        unsigned bin = (v >> 10) & 1023u;
        atomicAdd(&ch[bin], 1u);
        atomicAdd(&cs[bin], __uint_as_float(v));
    }
    __syncthreads();
    int sel2, kk2;
    find_kth_par<1024>(ch, (sel1 < 0) ? 0 : kk1, &sel2, &kk2);
    float s2v = 0.f;
    for (int i = tid * 4; i < tid * 4 + 4; i++)
        if (sel2 >= 0 && i > sel2) s2v += cs[i];
    float sumhi2 = block_sum_f(s2v);

    __syncthreads();
    for (int i = tid; i < 1024; i += 256) { ch[i] = 0u; cs[i] = 0.f; }
    __syncthreads();
    if (sel2 >= 0) {
        for (unsigned i = tid; i < ncand; i += 256) {
            unsigned v = cand[(size_t)b * PP + i];
            if (((v >> 10) & 1023u) == (unsigned)sel2) {
                atomicAdd(&ch[v & 1023u], 1u);
                atomicAdd(&cs[v & 1023u], __uint_as_float(v));
            }
        }
    }
    __syncthreads();
    int sel3, needeq;
    find_kth_par<1024>(ch, (sel2 < 0) ? 0 : kk2, &sel3, &needeq);
    float s3v = 0.f;
    for (int i = tid * 4; i < tid * 4 + 4; i++)
        if (sel3 >= 0 && i > sel3) s3v += cs[i];
    float sumhi3 = block_sum_f(s3v);

    if (tid == 0) {
        float add = 0.f;
        if (sel3 >= 0 && needeq > 0) {
            unsigned Kstar = ((unsigned)sel1 << 20) | ((unsigned)sel2 << 10) | (unsigned)sel3;
            add = needeq * __uint_as_float(Kstar);
        }
        resn[b] = np;
        resk[b] = k;
        resc[b] = pcsum + negs[b] + sumhi2 + sumhi3 + add;
        resl[b] = locsum;
        __threadfence();                               // release
        lastflag = (atomicAdd(done, 1u) == BB - 1) ? 1 : 0;
    }
    __syncthreads();
    if (!lastflag) return;
    if (tid == 0) __threadfence();                     // acquire (tid0-only, L1 per-CU)
    __syncthreads();

    int n = 0, kk = 0; float c = 0.f, l = 0.f;
    if (tid < BB) { n = resn[tid]; kk = resk[tid]; c = resc[tid]; l = resl[tid]; }
    if (tid < 64) {
        for (int o = 8; o; o >>= 1) {
            n += __shfl_xor(n, o); kk += __shfl_xor(kk, o);
            c += __shfl_xor(c, o); l += __shfl_xor(l, o);
        }
    }
    if (tid == 0) {
        long long maskc = (long long)n + kk;
        float denom_loc = (float)((4 * n > 1) ? 4 * n : 1);
        float denom_cls = (float)((maskc > 1) ? maskc : 1);
        float loss_loc = l / denom_loc;
        float loss_cls = c / denom_cls;
        out[0] = (loss_cls + loss_loc) / (float)n;
        out[1] = loss_loc;
        out[2] = loss_cls;
    }
}

extern "C" void kernel_launch(void* const* d_in, const int* in_sizes, int n_in,
                              void* d_out, int out_size, void* d_ws, size_t ws_size,
                              hipStream_t stream)
{
    const float* loc_preds = (const float*)d_in[0];
    const float* cls_preds = (const float*)d_in[1];
    const float* priorbox  = (const float*)d_in[2];
    const float* targets   = (const float*)d_in[3];
    float* out = (float*)d_out;

    char* ws = (char*)d_ws;
    unsigned long long* bestp = (unsigned long long*)(ws + OFF_BESTP);
    unsigned* h1tot = (unsigned*)(ws + OFF_H1TOT);
    int*      nposp = (int*)(ws + OFF_NPOSP);
    float*    pcp   = (float*)(ws + OFF_PCP);
    float*    locp  = (float*)(ws + OFF_LOCP);
    unsigned* cidx  = (unsigned*)(ws + OFF_CIDX);
    float*    negs  = (float*)(ws + OFF_NEGS);
    unsigned* done  = (unsigned*)(ws + OFF_DONE);
    int*      resn  = (int*)(ws + OFF_RESN);
    int*      resk  = (int*)(ws + OFF_RESK);
    float*    resc  = (float*)(ws + OFF_RESC);
    float*    resl  = (float*)(ws + OFF_RESL);
    unsigned char* pu8 = (unsigned char*)(ws + OFF_PU8);
    unsigned* keys  = (unsigned*)(ws + OFF_KEYS);
    unsigned* cand  = (unsigned*)(ws + OFF_CAND);

    k_match<<<dim3(NCHM, BB), 256, 0, stream>>>(priorbox, targets, bestp, pu8,
                                                h1tot, cidx, negs, done);
    k_loss<<<dim3(NCHL, BB), 256, 0, stream>>>(loc_preds, cls_preds, priorbox, targets,
                                               bestp, pu8, keys, h1tot,
                                               nposp, pcp, locp);
    k_compact<<<dim3(NCC, BB), 256, 0, stream>>>(keys, h1tot, nposp, cand, cidx, negs);
    k_select<<<BB, 256, 0, stream>>>(cand, cidx, h1tot, nposp, pcp, locp, negs,
                                     resn, resk, resc, resl, done, out);
}

// Round 15
// 99.501 us; speedup vs baseline: 9.1726x; 1.2605x over previous
//
#include <hip/hip_runtime.h>

#define BB 16
#define PP 131072
#define GG 64
#define THRESH 0.35f
#define EXPL 0.086f          // large-class raster expansion (max half-extent + slop)
#define EXPS 0.0495f         // small-class raster expansion
#define CLSB 0.049f          // class boundary on max(hx,hy)
#define NCELL 32             // 32x32 cell grid
#define NCHM 64              // match chunks per image
#define CPM 2048
#define NCHL 64              // loss chunks per image
#define CPL 2048
#define NCC 64               // compact chunks per image
#define CPC 2048

// ---------------- workspace layout (bytes) ----------------
// No host-side zeroing: partials unconditional; cidx/negs/done zeroed by k_match
// (consumed >=2 kernel boundaries later).
#define OFF_BESTP   0          // u64[BB][NCHM][64]  524288  (plain stores)
#define OFF_H1TOT   524288     // u32[BB][4096]      262144  (zeroed by k_match)
#define OFF_NPOSP   786432     // i32[BB][NCHL]      4096
#define OFF_PCP     790528     // f32[BB][NCHL]      4096
#define OFF_LOCP    794624     // f32[BB][NCHL]      4096
#define OFF_CIDX    798720     // u32[BB]            64
#define OFF_NEGS    798784     // f32[BB]            64
#define OFF_DONE    798848     // u32                64
#define OFF_RESN    798912     // i32[BB]
#define OFF_RESK    798976     // i32[BB]
#define OFF_RESC    799040     // f32[BB]
#define OFF_RESL    799104     // f32[BB]
#define OFF_PU8     799168     // u8[BB*PP]   2097152
#define OFF_KEYS    2896320    // u32[BB*PP]  8388608
#define OFF_CAND    11284928   // u32[BB*PP]  8388608   (total ~19.7 MB)

// ---------------- kernel 1: raster 2-class masks + match (single u64 walk) ----------
// grid (NCHM, BB) x 256; 8 priors/thread. Single walk, per-visit ds_max_u64 on
// packed (iou_bits<<32 | ~p) — R14 proved u64 LDS atomicMax is native (2-walk
// doubled time, per-visit cost unchanged). Small priors (max half-extent <=
// 0.049) walk a tighter mask: ~2.5 avg set bits vs ~4.8.
__global__ __launch_bounds__(256) void k_match(
    const float* __restrict__ priorbox, const float* __restrict__ targets,
    unsigned long long* __restrict__ bestp, unsigned char* __restrict__ pu8,
    unsigned* __restrict__ h1tot, unsigned* __restrict__ cidx,
    float* __restrict__ negs, unsigned* __restrict__ done)
{
    __shared__ unsigned mskS[2 * NCELL * NCELL];       // small-class mask (8KB)
    __shared__ unsigned mskL[2 * NCELL * NCELL];       // large-class mask (8KB)
    __shared__ float4 gxy[GG];
    __shared__ unsigned long long sbest[GG];
    const int b = blockIdx.y, chunk = blockIdx.x, tid = threadIdx.x;

    if (tid < 64) h1tot[b * 4096 + chunk * 64 + tid] = 0u;
    if (chunk == 0 && tid == 0) { cidx[b] = 0u; negs[b] = 0.f; if (b == 0) *done = 0u; }
    for (int i = tid; i < 2 * NCELL * NCELL; i += 256) { mskS[i] = 0u; mskL[i] = 0u; }
    if (tid < GG) {
        const float* t = targets + (size_t)(b * GG + tid) * 5;
        gxy[tid] = make_float4(t[1], t[0], t[3], t[2]); // gts = t[[1,0,3,2]]
        sbest[tid] = 0ull;
    }
    __syncthreads();

    {   // rasterize expanded gt boxes into both cell bitmasks
        const int g = tid & 63, strip = tid >> 6;
        float4 a = gxy[g];
        unsigned bit = 1u << (g & 31);
        const int word = g >> 5;
        {   // small-class mask (expansion EXPS)
            int cx0 = max(0, (int)((a.x - EXPS) * (float)NCELL));
            int cx1 = min(NCELL - 1, (int)ceilf((a.z + EXPS) * (float)NCELL) - 1);
            int cy0 = max(0, (int)((a.y - EXPS) * (float)NCELL));
            int cy1 = min(NCELL - 1, (int)ceilf((a.w + EXPS) * (float)NCELL) - 1);
            for (int cy = cy0 + strip; cy <= cy1; cy += 4)
                for (int cx = cx0; cx <= cx1; cx++)
                    atomicOr(&mskS[2 * (cy * NCELL + cx) + word], bit);
        }
        {   // large-class mask (expansion EXPL)
            int cx0 = max(0, (int)((a.x - EXPL) * (float)NCELL));
            int cx1 = min(NCELL - 1, (int)ceilf((a.z + EXPL) * (float)NCELL) - 1);
            int cy0 = max(0, (int)((a.y - EXPL) * (float)NCELL));
            int cy1 = min(NCELL - 1, (int)ceilf((a.w + EXPL) * (float)NCELL) - 1);
            for (int cy = cy0 + strip; cy <= cy1; cy += 4)
                for (int cx = cx0; cx <= cx1; cx++)
                    atomicOr(&mskL[2 * (cy * NCELL + cx) + word], bit);
        }
    }
    __syncthreads();

#pragma unroll
    for (int j = 0; j < 8; j++) {
        const int p = chunk * CPM + j * 256 + tid;
        float4 pr = *reinterpret_cast<const float4*>(priorbox + (size_t)p * 4);
        float hx = 0.5f * pr.z, hy = 0.5f * pr.w;
        float px1 = pr.x - hx, py1 = pr.y - hy;
        float px2 = pr.x + hx, py2 = pr.y + hy;
        float par = (px2 - px1) * (py2 - py1);
        int cx = min(NCELL - 1, max(0, (int)(pr.x * (float)NCELL)));
        int cy = min(NCELL - 1, max(0, (int)(pr.y * (float)NCELL)));
        const unsigned* mb = (fmaxf(hx, hy) <= CLSB) ? mskS : mskL;
        uint2 mm = *reinterpret_cast<const uint2*>(&mb[2 * (cy * NCELL + cx)]);
        unsigned long long m = ((unsigned long long)mm.y << 32) | mm.x;
        const unsigned long long notp = (unsigned long long)(~(unsigned)p);
        float bv = -1.f; int bg = 0;
        while (m) {
            // two set bits per iteration: two independent LDS reads in flight
            const int g0 = __ffsll(m) - 1; m &= m - 1;
            const bool has1 = (m != 0ull);
            const int g1 = has1 ? (__ffsll(m) - 1) : g0;
            if (has1) m &= m - 1;
            float4 a0 = gxy[g0];
            float4 a1 = gxy[g1];
            float w0 = fmaxf(fminf(a0.z, px2) - fmaxf(a0.x, px1), 0.f);
            float h0 = fmaxf(fminf(a0.w, py2) - fmaxf(a0.y, py1), 0.f);
            float w1 = fmaxf(fminf(a1.z, px2) - fmaxf(a1.x, px1), 0.f);
            float h1 = fmaxf(fminf(a1.w, py2) - fmaxf(a1.y, py1), 0.f);
            float ar0 = (a0.z - a0.x) * (a0.w - a0.y);
            float ar1 = (a1.z - a1.x) * (a1.w - a1.y);
            float i0 = w0 * h0, i1 = w1 * h1;
            float v0 = i0 * __builtin_amdgcn_rcpf(ar0 + par - i0);
            float v1 = i1 * __builtin_amdgcn_rcpf(ar1 + par - i1);
            if (v0 > bv) { bv = v0; bg = g0; }          // ascending g: first-max kept
            if (has1 && v1 > bv) { bv = v1; bg = g1; }
            if (v0 > 0.f)
                atomicMax(&sbest[g0],
                          (((unsigned long long)__float_as_uint(v0)) << 32) | notp);
            if (has1 && v1 > 0.f)
                atomicMax(&sbest[g1],
                          (((unsigned long long)__float_as_uint(v1)) << 32) | notp);
        }
        pu8[(size_t)b * PP + p] = (unsigned char)(bg | ((bv >= THRESH) ? 0x80 : 0));
    }

    __syncthreads();
    if (tid < GG) bestp[(b * NCHM + chunk) * GG + tid] = sbest[tid];   // plain store
}

// ---------------- kernel 2: loss + keys + global hist (bred folded in) ----------------
// grid (NCHL, BB) x 256; 8 priors/thread.
__global__ __launch_bounds__(256) void k_loss(
    const float* __restrict__ loc_preds, const float* __restrict__ cls_preds,
    const float* __restrict__ priorbox, const float* __restrict__ targets,
    const unsigned long long* __restrict__ bestp, const unsigned char* __restrict__ pu8,
    unsigned* __restrict__ keys, unsigned* __restrict__ h1tot,
    int* __restrict__ nposp, float* __restrict__ pcp, float* __restrict__ locp)
{
    __shared__ unsigned hcnt[4096];
    __shared__ unsigned ovr[CPL];                      // forced-pos: g+1, max = later-g
    __shared__ float4 gxy[GG];
    __shared__ float glab[GG];
    __shared__ float sred[8];
    __shared__ int sredi[4];
    const int b = blockIdx.y, chunk = blockIdx.x, tid = threadIdx.x;
    const int lane = tid & 63, wid = tid >> 6;

    for (int i = tid; i < 4096; i += 256) hcnt[i] = 0u;
    for (int i = tid; i < CPL; i += 256) ovr[i] = 0u;
    if (tid < GG) {
        const float* t = targets + (size_t)(b * GG + tid) * 5;
        gxy[tid] = make_float4(t[1], t[0], t[3], t[2]);
        glab[tid] = t[4];
    }
    __syncthreads();
    if (tid < GG) {                                    // inline chunk reduce (ex-k_bred)
        unsigned long long m = 0ull;
#pragma unroll 8
        for (int c = 0; c < NCHM; c++) {
            unsigned long long v = bestp[(b * NCHM + c) * GG + tid];
            m = v > m ? v : m;
        }
        if (m) {
            unsigned p = ~((unsigned)(m & 0xFFFFFFFFull));
            if ((int)(p >> 11) == chunk)
                atomicMax(&ovr[p & (CPL - 1)], (unsigned)tid + 1u);  // later-g wins
        }
    }
    __syncthreads();

    float locpart = 0.f, clspart = 0.f; int cnt = 0;
#pragma unroll
    for (int j = 0; j < 8; j++) {
        const int plocal = j * 256 + tid;
        const size_t ip = (size_t)b * PP + chunk * CPL + plocal;
        const unsigned m8 = pu8[ip];
        int g = m8 & 63;
        bool pos = (m8 >> 7) != 0;
        const unsigned o = ovr[plocal];
        if (o) { pos = true; g = (int)o - 1; }
        const float2 cl = *reinterpret_cast<const float2*>(cls_preds + ip * 2);
        const float mx = fmaxf(cl.x, cl.y);
        const float lse = mx + log1pf(expf(fminf(cl.x, cl.y) - mx));
        unsigned key = 0u;
        if (pos && glab[g] > 0.f) {
            float gathered = (((int)glab[g]) == 0) ? cl.x : cl.y;
            clspart += lse - gathered;
            cnt++;
            const int p = chunk * CPL + plocal;
            float4 pr = *reinterpret_cast<const float4*>(priorbox + (size_t)p * 4);
            float4 gt = gxy[g];
            float gcx = ((gt.x + gt.z) * 0.5f - pr.x) / (0.1f * pr.z);
            float gcy = ((gt.y + gt.w) * 0.5f - pr.y) / (0.1f * pr.w);
            float gw = logf((gt.z - gt.x) / pr.z) / 0.2f;
            float gh = logf((gt.w - gt.y) / pr.w) / 0.2f;
            float4 lp = *reinterpret_cast<const float4*>(loc_preds + ip * 4);
            float d0 = lp.x - gcx, d1 = lp.y - gcy, d2 = lp.z - gw, d3 = lp.w - gh;
            float a0 = fabsf(d0), a1 = fabsf(d1), a2 = fabsf(d2), a3 = fabsf(d3);
            locpart += ((a0 < 1.f) ? 0.5f * d0 * d0 : a0 - 0.5f)
                     + ((a1 < 1.f) ? 0.5f * d1 * d1 : a1 - 0.5f)
                     + ((a2 < 1.f) ? 0.5f * d2 * d2 : a2 - 0.5f)
                     + ((a3 < 1.f) ? 0.5f * d3 * d3 : a3 - 0.5f);
        } else {
            float lc = lse - cl.x;                     // > 0 strictly for negs
            key = __float_as_uint(lc);
            atomicAdd(&hcnt[key >> 20], 1u);
        }
        keys[ip] = key;
    }

    for (int o = 32; o; o >>= 1) {
        locpart += __shfl_xor(locpart, o);
        clspart += __shfl_xor(clspart, o);
        cnt     += __shfl_xor(cnt, o);
    }
    if (lane == 0) { sred[wid] = locpart; sred[4 + wid] = clspart; sredi[wid] = cnt; }
    __syncthreads();
    if (tid == 0) {
        float l = sred[0] + sred[1] + sred[2] + sred[3];
        float c = sred[4] + sred[5] + sred[6] + sred[7];
        int n = sredi[0] + sredi[1] + sredi[2] + sredi[3];
        nposp[b * NCHL + chunk] = n;
        pcp[b * NCHL + chunk] = c;
        locp[b * NCHL + chunk] = l;
    }
    __syncthreads();
    for (int i = tid; i < 4096; i += 256) {
        unsigned cc = hcnt[i];
        if (cc) atomicAdd(&h1tot[b * 4096 + i], cc);
    }
}

// ---------------- parallel descending k-th finder (256-thread block) ----------------
template <int NBINS>
__device__ void find_kth_par(const unsigned* __restrict__ h, int k, int* sel, int* krem)
{
    constexpr int PER = NBINS / 256;
    __shared__ unsigned wsum_[4];
    __shared__ int res_[2];
    const int tid = threadIdx.x, lane = tid & 63, wid = tid >> 6;
    __syncthreads();
    unsigned s = 0;
#pragma unroll
    for (int i = 0; i < PER; i++) s += h[NBINS - 1 - (tid * PER + i)];
    unsigned incl = s;
    for (int d = 1; d < 64; d <<= 1) {
        unsigned t = __shfl_up(incl, d);
        if (lane >= d) incl += t;
    }
    if (lane == 63) wsum_[wid] = incl;
    if (tid == 0) { res_[0] = -1; res_[1] = 0; }
    __syncthreads();
    unsigned woff = 0;
    for (int w = 0; w < 4; w++) woff += (w < wid) ? wsum_[w] : 0u;
    const unsigned texcl = woff + incl - s;
    if (k > 0 && texcl < (unsigned)k && texcl + s >= (unsigned)k) {
        unsigned run = texcl;
        for (int i = 0; i < PER; i++) {
            unsigned hv = h[NBINS - 1 - (tid * PER + i)];
            run += hv;
            if (run >= (unsigned)k) {
                res_[0] = NBINS - 1 - (tid * PER + i);
                res_[1] = k - (int)(run - hv);
                break;
            }
        }
    }
    __syncthreads();
    *sel = res_[0]; *krem = res_[1];
}

__device__ float block_sum_f(float v)
{
    __shared__ float rs[4];
    const int tid = threadIdx.x;
    __syncthreads();
    for (int o = 32; o; o >>= 1) v += __shfl_xor(v, o);
    if ((tid & 63) == 0) rs[tid >> 6] = v;
    __syncthreads();
    return rs[0] + rs[1] + rs[2] + rs[3];
}

__device__ int np_of_image(const int* __restrict__ nposp, int b)
{
    __shared__ int snp;
    const int tid = threadIdx.x;
    int v = (tid < 64) ? nposp[b * NCHL + tid] : 0;
    if (tid < 64) {
        for (int o = 32; o; o >>= 1) v += __shfl_xor(v, o);
        if (tid == 0) snp = v;
    }
    __syncthreads();
    return snp;
}

// ---------------- kernel 3: sel1 (redundant) + negsum + compact ----------------
// grid (NCC, BB) x 256, 8 keys/thread; 1 returning atomic per block.
__global__ __launch_bounds__(256) void k_compact(
    const unsigned* __restrict__ keys, const unsigned* __restrict__ h1tot,
    const int* __restrict__ nposp, unsigned* __restrict__ cand,
    unsigned* __restrict__ cidx, float* __restrict__ negs)
{
    __shared__ unsigned wcnt[4], wbase[4];
    __shared__ unsigned bbase;
    const int b = blockIdx.y, chunk = blockIdx.x, tid = threadIdx.x;
    const int lane = tid & 63, wid = tid >> 6;

    unsigned kv[8];
#pragma unroll
    for (int j = 0; j < 8; j++)
        kv[j] = keys[(size_t)b * PP + chunk * CPC + j * 256 + tid];

    const int np = np_of_image(nposp, b);
    const int k = min(3 * np, PP - 1);
    int sel1, kk1;
    find_kth_par<4096>(h1tot + b * 4096, k, &sel1, &kk1);
    const unsigned s1 = (unsigned)sel1;                // -1 matches nothing

    float nv = 0.f;
    if (sel1 >= 0) {
#pragma unroll
        for (int j = 0; j < 8; j++)
            if ((kv[j] >> 20) > s1) nv += __uint_as_float(kv[j]);
    }
    float nsum = block_sum_f(nv);
    if (tid == 0 && nsum != 0.f) atomicAdd(&negs[b], nsum);

    unsigned long long mv[8];
    unsigned wn = 0;
#pragma unroll
    for (int j = 0; j < 8; j++) {
        mv[j] = __ballot((kv[j] >> 20) == s1);
        wn += (unsigned)__popcll(mv[j]);
    }
    if (lane == 0) wcnt[wid] = wn;
    __syncthreads();
    if (tid == 0) {
        unsigned run = 0;
        for (int w = 0; w < 4; w++) { wbase[w] = run; run += wcnt[w]; }
        bbase = run ? atomicAdd(&cidx[b], run) : 0u;
    }
    __syncthreads();
    unsigned run = bbase + wbase[wid];
    const unsigned long long lanemask = (1ull << lane) - 1ull;
#pragma unroll
    for (int j = 0; j < 8; j++) {
        if ((kv[j] >> 20) == s1)
            cand[(size_t)b * PP + run + (unsigned)__popcll(mv[j] & lanemask)] = kv[j];
        run += (unsigned)__popcll(mv[j]);
    }
}

// ---------------- kernel 4: exact top-k + per-image results + final (done-counter) ----
// grid BB x 256; last-done block combines the 3 outputs.
__global__ __launch_bounds__(256) void k_select(
    const unsigned* __restrict__ cand, const unsigned* __restrict__ cidx,
    const unsigned* __restrict__ h1tot, const int* __restrict__ nposp,
    const float* __restrict__ pcp, const float* __restrict__ locp,
    const float* __restrict__ negs,
    int* __restrict__ resn, int* __restrict__ resk,
    float* __restrict__ resc, float* __restrict__ resl,
    unsigned* __restrict__ done, float* __restrict__ out)
{
    __shared__ unsigned ch[1024];
    __shared__ float cs[1024];
    __shared__ int lastflag;
    const int b = blockIdx.x, tid = threadIdx.x;

    const int np = np_of_image(nposp, b);
    const int k = min(3 * np, PP - 1);
    int sel1, kk1;
    find_kth_par<4096>(h1tot + b * 4096, k, &sel1, &kk1);
    const unsigned ncand = cidx[b];

    float pv = (tid < 64) ? pcp[b * NCHL + tid] : 0.f;
    float lv = (tid < 64) ? locp[b * NCHL + tid] : 0.f;
    float pcsum = block_sum_f(pv);
    float locsum = block_sum_f(lv);

    for (int i = tid; i < 1024; i += 256) { ch[i] = 0u; cs[i] = 0.f; }
    __syncthreads();
    for (unsigned i = tid; i < ncand; i += 256) {
        unsigned v = cand[(size_t)b * PP + i];
        unsigned bin = (v >> 10) & 1023u;
        atomicAdd(&ch[bin], 1u);
        atomicAdd(&cs[bin], __uint_as_float(v));
    }
    __syncthreads();
    int sel2, kk2;
    find_kth_par<1024>(ch, (sel1 < 0) ? 0 : kk1, &sel2, &kk2);
    float s2v = 0.f;
    for (int i = tid * 4; i < tid * 4 + 4; i++)
        if (sel2 >= 0 && i > sel2) s2v += cs[i];
    float sumhi2 = block_sum_f(s2v);

    __syncthreads();
    for (int i = tid; i < 1024; i += 256) { ch[i] = 0u; cs[i] = 0.f; }
    __syncthreads();
    if (sel2 >= 0) {
        for (unsigned i = tid; i < ncand; i += 256) {
            unsigned v = cand[(size_t)b * PP + i];
            if (((v >> 10) & 1023u) == (unsigned)sel2) {
                atomicAdd(&ch[v & 1023u], 1u);
                atomicAdd(&cs[v & 1023u], __uint_as_float(v));
            }
        }
    }
    __syncthreads();
    int sel3, needeq;
    find_kth_par<1024>(ch, (sel2 < 0) ? 0 : kk2, &sel3, &needeq);
    float s3v = 0.f;
    for (int i = tid * 4; i < tid * 4 + 4; i++)
        if (sel3 >= 0 && i > sel3) s3v += cs[i];
    float sumhi3 = block_sum_f(s3v);

    if (tid == 0) {
        float add = 0.f;
        if (sel3 >= 0 && needeq > 0) {
            unsigned Kstar = ((unsigned)sel1 << 20) | ((unsigned)sel2 << 10) | (unsigned)sel3;
            add = needeq * __uint_as_float(Kstar);
        }
        resn[b] = np;
        resk[b] = k;
        resc[b] = pcsum + negs[b] + sumhi2 + sumhi3 + add;
        resl[b] = locsum;
        __threadfence();                               // release
        lastflag = (atomicAdd(done, 1u) == BB - 1) ? 1 : 0;
    }
    __syncthreads();
    if (!lastflag) return;
    if (tid == 0) __threadfence();                     // acquire (tid0-only, L1 per-CU)
    __syncthreads();

    int n = 0, kk = 0; float c = 0.f, l = 0.f;
    if (tid < BB) { n = resn[tid]; kk = resk[tid]; c = resc[tid]; l = resl[tid]; }
    if (tid < 64) {
        for (int o = 8; o; o >>= 1) {
            n += __shfl_xor(n, o); kk += __shfl_xor(kk, o);
            c += __shfl_xor(c, o); l += __shfl_xor(l, o);
        }
    }
    if (tid == 0) {
        long long maskc = (long long)n + kk;
        float denom_loc = (float)((4 * n > 1) ? 4 * n : 1);
        float denom_cls = (float)((maskc > 1) ? maskc : 1);
        float loss_loc = l / denom_loc;
        float loss_cls = c / denom_cls;
        out[0] = (loss_cls + loss_loc) / (float)n;
        out[1] = loss_loc;
        out[2] = loss_cls;
    }
}

extern "C" void kernel_launch(void* const* d_in, const int* in_sizes, int n_in,
                              void* d_out, int out_size, void* d_ws, size_t ws_size,
                              hipStream_t stream)
{
    const float* loc_preds = (const float*)d_in[0];
    const float* cls_preds = (const float*)d_in[1];
    const float* priorbox  = (const float*)d_in[2];
    const float* targets   = (const float*)d_in[3];
    float* out = (float*)d_out;

    char* ws = (char*)d_ws;
    unsigned long long* bestp = (unsigned long long*)(ws + OFF_BESTP);
    unsigned* h1tot = (unsigned*)(ws + OFF_H1TOT);
    int*      nposp = (int*)(ws + OFF_NPOSP);
    float*    pcp   = (float*)(ws + OFF_PCP);
    float*    locp  = (float*)(ws + OFF_LOCP);
    unsigned* cidx  = (unsigned*)(ws + OFF_CIDX);
    float*    negs  = (float*)(ws + OFF_NEGS);
    unsigned* done  = (unsigned*)(ws + OFF_DONE);
    int*      resn  = (int*)(ws + OFF_RESN);
    int*      resk  = (int*)(ws + OFF_RESK);
    float*    resc  = (float*)(ws + OFF_RESC);
    float*    resl  = (float*)(ws + OFF_RESL);
    unsigned char* pu8 = (unsigned char*)(ws + OFF_PU8);
    unsigned* keys  = (unsigned*)(ws + OFF_KEYS);
    unsigned* cand  = (unsigned*)(ws + OFF_CAND);

    k_match<<<dim3(NCHM, BB), 256, 0, stream>>>(priorbox, targets, bestp, pu8,
                                                h1tot, cidx, negs, done);
    k_loss<<<dim3(NCHL, BB), 256, 0, stream>>>(loc_preds, cls_preds, priorbox, targets,
                                               bestp, pu8, keys, h1tot,
                                               nposp, pcp, locp);
    k_compact<<<dim3(NCC, BB), 256, 0, stream>>>(keys, h1tot, nposp, cand, cidx, negs);
    k_select<<<BB, 256, 0, stream>>>(cand, cidx, h1tot, nposp, pcp, locp, negs,
                                     resn, resk, resc, resl, done, out);
}